// Round 2
// baseline (133.071 us; speedup 1.0000x reference)
//
#include <hip/hip_runtime.h>
#include <hip/hip_bf16.h>

// Problem constants (from reference)
#define N_NODES 4096
#define F_IN    128
#define UNITS   64
#define HEADS   4

// ---------------------------------------------------------------------------
// Kernel 1: x = inputs @ w  [N,64], e1 = x @ attn_w1 [N,4], e2 = x @ attn_w2,
//           plus per-block partial column sums of x.
// 256 blocks x 256 threads; each block handles 16 rows.
// ---------------------------------------------------------------------------
__global__ __launch_bounds__(256) void k1(const float* __restrict__ inputs,
                                          const float* __restrict__ w,
                                          const float* __restrict__ aw1,
                                          const float* __restrict__ aw2,
                                          float* __restrict__ x,
                                          float* __restrict__ e1,
                                          float* __restrict__ e2,
                                          float* __restrict__ partial) {
    __shared__ float w_lds[F_IN * UNITS];     // 32 KB
    __shared__ float in_lds[16 * F_IN];       // 8 KB
    __shared__ float x_lds[16 * 65];          // padded stride 65 (bank-conflict fix)

    const int t = threadIdx.x;
    const int b = blockIdx.x;
    const int row0 = b * 16;

    // stage w (coalesced, L2-cached across blocks)
    for (int k = t; k < F_IN * UNITS; k += 256) w_lds[k] = w[k];
    // stage 16 input rows
    for (int k = t; k < 16 * F_IN; k += 256) in_lds[k] = inputs[(size_t)row0 * F_IN + k];
    __syncthreads();

    // each thread computes 4 x-elements: u = t&63, rows rg*4+s
    const int u = t & 63;
    const int rg = t >> 6;
    for (int s = 0; s < 4; s++) {
        const int r = rg * 4 + s;
        float acc = 0.f;
#pragma unroll 8
        for (int k = 0; k < F_IN; k++)
            acc = fmaf(in_lds[r * F_IN + k], w_lds[k * UNITS + u], acc);
        x_lds[r * 65 + u] = acc;
        x[(size_t)(row0 + r) * UNITS + u] = acc;
    }
    __syncthreads();

    // e1/e2: 16 rows x 4 heads x 2 matrices = 128 tasks
    if (t < 128) {
        const int r = t >> 3;
        const int rem = t & 7;
        const int h = rem & 3;
        const bool first = rem < 4;
        const float* aw = first ? aw1 : aw2;
        float s = 0.f;
#pragma unroll 8
        for (int uu = 0; uu < UNITS; uu++)
            s += x_lds[r * 65 + uu] * aw[uu * HEADS + h];
        (first ? e1 : e2)[(size_t)(row0 + r) * HEADS + h] = s;
    }

    // partial column sums of x over this block's 16 rows
    if (t < 64) {
        float s = 0.f;
#pragma unroll
        for (int r = 0; r < 16; r++) s += x_lds[r * 65 + t];
        partial[b * 64 + t] = s;
    }
}

// ---------------------------------------------------------------------------
// Kernel 1b: S[u] = sum over 256 block-partials
// ---------------------------------------------------------------------------
__global__ __launch_bounds__(64) void k1b(const float* __restrict__ partial,
                                          float* __restrict__ S) {
    const int t = threadIdx.x;
    float s = 0.f;
    for (int b = 0; b < 256; b++) s += partial[b * 64 + t];
    S[t] = s;
}

// ---------------------------------------------------------------------------
// Kernel 2: per row i — scan adj row, compact neighbors, sparse-corrected
// softmax aggregation. out[i, h*64+u] = relu((S[u]+acc)/(N+den)).
// 4096 blocks x 256 threads (thread t -> h = t>>6, u = t&63).
// ---------------------------------------------------------------------------
__global__ __launch_bounds__(256) void k2(const float* __restrict__ adj,
                                          const float* __restrict__ x,
                                          const float* __restrict__ e1,
                                          const float* __restrict__ e2,
                                          const float* __restrict__ S,
                                          float* __restrict__ out) {
    __shared__ unsigned short nbr[N_NODES];   // 8 KB — worst case all neighbors
    __shared__ int cnt;

    const int i = blockIdx.x;
    const int t = threadIdx.x;

    if (t == 0) cnt = 0;
    __syncthreads();

    // scan adjacency row as float4 (coalesced 16B/lane)
    const float4* arow = (const float4*)(adj + (size_t)i * N_NODES);
#pragma unroll
    for (int it = 0; it < 4; it++) {
        const int c = t + it * 256;            // 0..1023
        const float4 v = arow[c];
        const int base = c * 4;
        if (v.x != 0.f) nbr[atomicAdd(&cnt, 1)] = (unsigned short)(base + 0);
        if (v.y != 0.f) nbr[atomicAdd(&cnt, 1)] = (unsigned short)(base + 1);
        if (v.z != 0.f) nbr[atomicAdd(&cnt, 1)] = (unsigned short)(base + 2);
        if (v.w != 0.f) nbr[atomicAdd(&cnt, 1)] = (unsigned short)(base + 3);
    }
    __syncthreads();

    const int n = cnt;
    const int h = t >> 6;
    const int u = t & 63;
    const float e1h = e1[(size_t)i * HEADS + h];

    float acc = 0.f;
    float den = 0.f;
#pragma unroll 2
    for (int k = 0; k < n; k++) {
        const int j = nbr[k];                          // LDS broadcast
        const float sc = fmaxf(e1h + e2[j * HEADS + h], 0.f);
        const float wgt = __expf(sc) - 1.f;            // exp(score) - exp(0)
        den += wgt;
        acc = fmaf(wgt, x[j * UNITS + u], acc);        // coalesced 256B/wave, L2-hot
    }

    const float numer = S[u] + acc;
    const float denom = (float)N_NODES + den;
    out[(size_t)i * (HEADS * UNITS) + t] = fmaxf(numer / denom, 0.f);
}

// ---------------------------------------------------------------------------
extern "C" void kernel_launch(void* const* d_in, const int* in_sizes, int n_in,
                              void* d_out, int out_size, void* d_ws, size_t ws_size,
                              hipStream_t stream) {
    const float* inputs = (const float*)d_in[0];
    const float* adj    = (const float*)d_in[1];
    const float* w      = (const float*)d_in[2];
    const float* aw1    = (const float*)d_in[3];
    const float* aw2    = (const float*)d_in[4];
    float* out = (float*)d_out;

    // workspace layout (floats): x[262144] | e1[16384] | e2[16384] | partial[16384] | S[64]
    float* ws = (float*)d_ws;
    float* x       = ws;
    float* e1      = ws + 262144;
    float* e2      = ws + 262144 + 16384;
    float* partial = ws + 262144 + 2 * 16384;
    float* S       = ws + 262144 + 3 * 16384;

    k1<<<256, 256, 0, stream>>>(inputs, w, aw1, aw2, x, e1, e2, partial);
    k1b<<<1, 64, 0, stream>>>(partial, S);
    k2<<<N_NODES, 256, 0, stream>>>(adj, x, e1, e2, S, out);
}

// Round 3
// 121.136 us; speedup vs baseline: 1.0985x; 1.0985x over previous
//
#include <hip/hip_runtime.h>
#include <hip/hip_bf16.h>

// Problem constants (from reference)
#define N_NODES 4096
#define F_IN    128
#define UNITS   64
#define HEADS   4
#define WT_PITCH 132   // 128 + 4 pad (float4-granular) for w-transpose LDS tile
#define CHUNK   128    // neighbor chunk for k2 (expected n ~41, max ~80)

// ---------------------------------------------------------------------------
// Kernel 1: x = inputs @ w  [N,64], e1 = x @ attn_w1 [N,4], e2 = x @ attn_w2,
//           plus per-block partial column sums of x.
// 256 blocks x 256 threads; each block handles 16 rows.
// w staged TRANSPOSED in LDS so the inner loop is float4 x float4.
// ---------------------------------------------------------------------------
__global__ __launch_bounds__(256) void k1(const float* __restrict__ inputs,
                                          const float* __restrict__ w,
                                          const float* __restrict__ aw1,
                                          const float* __restrict__ aw2,
                                          float* __restrict__ x,
                                          float* __restrict__ e1,
                                          float* __restrict__ e2,
                                          float* __restrict__ partial) {
    __shared__ float w_t[UNITS * WT_PITCH];   // w_t[u*132 + k] = w[k*64+u]  (33 KB)
    __shared__ float in_lds[16 * F_IN];       // 8 KB
    __shared__ float x_lds[16 * 65];          // padded stride 65

    const int t = threadIdx.x;
    const int b = blockIdx.x;
    const int row0 = b * 16;

    // stage w transposed (coalesced global read: consecutive t -> consecutive u)
    for (int idx = t; idx < F_IN * UNITS; idx += 256) {
        const int u = idx & 63;
        const int k = idx >> 6;
        w_t[u * WT_PITCH + k] = w[idx];
    }
    // stage 16 input rows (coalesced float4)
    {
        const float4* src = (const float4*)(inputs + (size_t)row0 * F_IN);
        float4* dst = (float4*)in_lds;
        for (int idx = t; idx < 16 * F_IN / 4; idx += 256) dst[idx] = src[idx];
    }
    __syncthreads();

    // thread u = t&63 handles column u for rows rg*4 .. rg*4+3
    const int u = t & 63;
    const int rg = t >> 6;
    float acc0 = 0.f, acc1 = 0.f, acc2 = 0.f, acc3 = 0.f;
    const float4* wrow = (const float4*)(w_t + u * WT_PITCH);
    const float4* i0 = (const float4*)(in_lds + (rg * 4 + 0) * F_IN);
    const float4* i1 = (const float4*)(in_lds + (rg * 4 + 1) * F_IN);
    const float4* i2 = (const float4*)(in_lds + (rg * 4 + 2) * F_IN);
    const float4* i3 = (const float4*)(in_lds + (rg * 4 + 3) * F_IN);
#pragma unroll 8
    for (int c = 0; c < F_IN / 4; c++) {
        const float4 wv = wrow[c];
        float4 v;
        v = i0[c]; acc0 = fmaf(wv.x, v.x, fmaf(wv.y, v.y, fmaf(wv.z, v.z, fmaf(wv.w, v.w, acc0))));
        v = i1[c]; acc1 = fmaf(wv.x, v.x, fmaf(wv.y, v.y, fmaf(wv.z, v.z, fmaf(wv.w, v.w, acc1))));
        v = i2[c]; acc2 = fmaf(wv.x, v.x, fmaf(wv.y, v.y, fmaf(wv.z, v.z, fmaf(wv.w, v.w, acc2))));
        v = i3[c]; acc3 = fmaf(wv.x, v.x, fmaf(wv.y, v.y, fmaf(wv.z, v.z, fmaf(wv.w, v.w, acc3))));
    }
    x_lds[(rg * 4 + 0) * 65 + u] = acc0;
    x_lds[(rg * 4 + 1) * 65 + u] = acc1;
    x_lds[(rg * 4 + 2) * 65 + u] = acc2;
    x_lds[(rg * 4 + 3) * 65 + u] = acc3;
    x[(size_t)(row0 + rg * 4 + 0) * UNITS + u] = acc0;
    x[(size_t)(row0 + rg * 4 + 1) * UNITS + u] = acc1;
    x[(size_t)(row0 + rg * 4 + 2) * UNITS + u] = acc2;
    x[(size_t)(row0 + rg * 4 + 3) * UNITS + u] = acc3;
    __syncthreads();

    // e1/e2: 16 rows x 4 heads x 2 matrices = 128 tasks
    if (t < 128) {
        const int r = t >> 3;
        const int rem = t & 7;
        const int h = rem & 3;
        const bool first = rem < 4;
        const float* aw = first ? aw1 : aw2;
        float s = 0.f;
#pragma unroll 8
        for (int uu = 0; uu < UNITS; uu++)
            s += x_lds[r * 65 + uu] * aw[uu * HEADS + h];
        (first ? e1 : e2)[(size_t)(row0 + r) * HEADS + h] = s;
    }

    // partial column sums of x over this block's 16 rows
    if (t < 64) {
        float s = 0.f;
#pragma unroll
        for (int r = 0; r < 16; r++) s += x_lds[r * 65 + t];
        partial[b * 64 + t] = s;
    }
}

// ---------------------------------------------------------------------------
// Kernel 1b: S[u] = sum over 256 block-partials (256 threads, 4-way split)
// ---------------------------------------------------------------------------
__global__ __launch_bounds__(256) void k1b(const float* __restrict__ partial,
                                           float* __restrict__ S) {
    __shared__ float red[4][64];
    const int u = threadIdx.x & 63;
    const int q = threadIdx.x >> 6;
    float s = 0.f;
#pragma unroll 8
    for (int b = q; b < 256; b += 4) s += partial[b * 64 + u];
    red[q][u] = s;
    __syncthreads();
    if (threadIdx.x < 64) S[u] = red[0][u] + red[1][u] + red[2][u] + red[3][u];
}

// ---------------------------------------------------------------------------
// Kernel 2: per row i — scan adj row, compact neighbors, two-phase sparse
// softmax-corrected aggregation.
//   phase A: threads 0..CHUNK-1 each compute wgt[k][0..3] (float4 e2 load, exp)
//   phase B: thread (h,u) loops k: 2 LDS broadcasts + 1 coalesced x load + 2 FMA
// out[i, h*64+u] = relu((S[u]+acc)/(N+den)).
// ---------------------------------------------------------------------------
__global__ __launch_bounds__(256) void k2(const float* __restrict__ adj,
                                          const float* __restrict__ x,
                                          const float* __restrict__ e1,
                                          const float* __restrict__ e2,
                                          const float* __restrict__ S,
                                          float* __restrict__ out) {
    __shared__ unsigned short nbr[N_NODES];   // 8 KB — worst case all neighbors
    __shared__ float wgt[CHUNK * 4];          // 2 KB — per-chunk weights (k-major, 4 heads)
    __shared__ int cnt;

    const int i = blockIdx.x;
    const int t = threadIdx.x;

    if (t == 0) cnt = 0;
    __syncthreads();

    // scan adjacency row as float4 (coalesced 16B/lane)
    const float4* arow = (const float4*)(adj + (size_t)i * N_NODES);
#pragma unroll
    for (int it = 0; it < 4; it++) {
        const int c = t + it * 256;            // 0..1023
        const float4 v = arow[c];
        const int base = c * 4;
        if (v.x != 0.f) nbr[atomicAdd(&cnt, 1)] = (unsigned short)(base + 0);
        if (v.y != 0.f) nbr[atomicAdd(&cnt, 1)] = (unsigned short)(base + 1);
        if (v.z != 0.f) nbr[atomicAdd(&cnt, 1)] = (unsigned short)(base + 2);
        if (v.w != 0.f) nbr[atomicAdd(&cnt, 1)] = (unsigned short)(base + 3);
    }
    __syncthreads();

    const int n = cnt;
    const int h = t >> 6;
    const int u = t & 63;

    // e1 row for this node (broadcast float4)
    const float4 e1v = *(const float4*)(e1 + (size_t)i * HEADS);

    float acc = 0.f;   // sum_k wgt[k][h] * x[j_k][u]
    float den = 0.f;   // sum_k wgt[k][h]

    for (int base = 0; base < n; base += CHUNK) {
        const int m = min(n - base, CHUNK);

        // phase A: compute weights for this chunk (threads 0..m-1)
        if (t < m) {
            const int j = nbr[base + t];
            const float4 e2v = *(const float4*)(e2 + (size_t)j * HEADS);
            float4 wv;
            wv.x = __expf(fmaxf(e1v.x + e2v.x, 0.f)) - 1.f;
            wv.y = __expf(fmaxf(e1v.y + e2v.y, 0.f)) - 1.f;
            wv.z = __expf(fmaxf(e1v.z + e2v.z, 0.f)) - 1.f;
            wv.w = __expf(fmaxf(e1v.w + e2v.w, 0.f)) - 1.f;
            *(float4*)(wgt + t * 4) = wv;
        }
        __syncthreads();

        // phase B: tight gather loop — all loads independent, unrollable
#pragma unroll 4
        for (int k = 0; k < m; k++) {
            const int j = nbr[base + k];       // LDS broadcast
            const float wv = wgt[k * 4 + h];   // LDS broadcast (h uniform per wave)
            den += wv;
            acc = fmaf(wv, x[j * UNITS + u], acc);  // coalesced 256B/wave, L2-hot
        }
        __syncthreads();   // protect wgt before next chunk overwrites
    }

    const float numer = S[u] + acc;
    const float denom = (float)N_NODES + den;
    out[(size_t)i * (HEADS * UNITS) + t] = fmaxf(numer / denom, 0.f);
}

// ---------------------------------------------------------------------------
extern "C" void kernel_launch(void* const* d_in, const int* in_sizes, int n_in,
                              void* d_out, int out_size, void* d_ws, size_t ws_size,
                              hipStream_t stream) {
    const float* inputs = (const float*)d_in[0];
    const float* adj    = (const float*)d_in[1];
    const float* w      = (const float*)d_in[2];
    const float* aw1    = (const float*)d_in[3];
    const float* aw2    = (const float*)d_in[4];
    float* out = (float*)d_out;

    // workspace layout (floats): x[262144] | e1[16384] | e2[16384] | partial[16384] | S[64]
    float* ws = (float*)d_ws;
    float* x       = ws;
    float* e1      = ws + 262144;
    float* e2      = ws + 262144 + 16384;
    float* partial = ws + 262144 + 2 * 16384;
    float* S       = ws + 262144 + 3 * 16384;

    k1<<<256, 256, 0, stream>>>(inputs, w, aw1, aw2, x, e1, e2, partial);
    k1b<<<1, 256, 0, stream>>>(partial, S);
    k2<<<N_NODES, 256, 0, stream>>>(adj, x, e1, e2, S, out);
}

// Round 4
// 119.199 us; speedup vs baseline: 1.1164x; 1.0163x over previous
//
#include <hip/hip_runtime.h>
#include <hip/hip_bf16.h>

// Problem constants (from reference)
#define N_NODES 4096
#define F_IN    128
#define UNITS   64
#define HEADS   4
#define WT_PITCH 132   // 128 + 4 pad (float4-granular) for w-transpose LDS tile
#define CHUNK   64     // neighbor chunk for k2 (expected n ~41, max ~70)

// ---------------------------------------------------------------------------
// Kernel 1: x = inputs @ w  [N,64], e1 = x @ attn_w1 [N,4], e2 = x @ attn_w2,
//           plus per-block partial column sums of x.
// 256 blocks x 256 threads; each block handles 16 rows.
// w staged TRANSPOSED in LDS so the inner loop is float4 x float4.
// ---------------------------------------------------------------------------
__global__ __launch_bounds__(256) void k1(const float* __restrict__ inputs,
                                          const float* __restrict__ w,
                                          const float* __restrict__ aw1,
                                          const float* __restrict__ aw2,
                                          float* __restrict__ x,
                                          float* __restrict__ e1,
                                          float* __restrict__ e2,
                                          float* __restrict__ partial) {
    __shared__ float w_t[UNITS * WT_PITCH];   // w_t[u*132 + k] = w[k*64+u]  (33 KB)
    __shared__ float in_lds[16 * F_IN];       // 8 KB
    __shared__ float x_lds[16 * 65];          // padded stride 65
    __shared__ float aw_lds[2 * UNITS * HEADS]; // aw1 then aw2 (2 KB)

    const int t = threadIdx.x;
    const int b = blockIdx.x;
    const int row0 = b * 16;

    // stage w transposed (coalesced global read: consecutive t -> consecutive u)
    for (int idx = t; idx < F_IN * UNITS; idx += 256) {
        const int u = idx & 63;
        const int k = idx >> 6;
        w_t[u * WT_PITCH + k] = w[idx];
    }
    // stage 16 input rows (coalesced float4)
    {
        const float4* src = (const float4*)(inputs + (size_t)row0 * F_IN);
        float4* dst = (float4*)in_lds;
        for (int idx = t; idx < 16 * F_IN / 4; idx += 256) dst[idx] = src[idx];
    }
    // stage attention vectors
    if (t < UNITS * HEADS) {
        aw_lds[t] = aw1[t];
        aw_lds[UNITS * HEADS + t] = aw2[t];
    }
    __syncthreads();

    // thread u = t&63 handles column u for rows rg*4 .. rg*4+3
    const int u = t & 63;
    const int rg = t >> 6;
    float acc0 = 0.f, acc1 = 0.f, acc2 = 0.f, acc3 = 0.f;
    const float4* wrow = (const float4*)(w_t + u * WT_PITCH);
    const float4* i0 = (const float4*)(in_lds + (rg * 4 + 0) * F_IN);
    const float4* i1 = (const float4*)(in_lds + (rg * 4 + 1) * F_IN);
    const float4* i2 = (const float4*)(in_lds + (rg * 4 + 2) * F_IN);
    const float4* i3 = (const float4*)(in_lds + (rg * 4 + 3) * F_IN);
#pragma unroll 8
    for (int c = 0; c < F_IN / 4; c++) {
        const float4 wv = wrow[c];
        float4 v;
        v = i0[c]; acc0 = fmaf(wv.x, v.x, fmaf(wv.y, v.y, fmaf(wv.z, v.z, fmaf(wv.w, v.w, acc0))));
        v = i1[c]; acc1 = fmaf(wv.x, v.x, fmaf(wv.y, v.y, fmaf(wv.z, v.z, fmaf(wv.w, v.w, acc1))));
        v = i2[c]; acc2 = fmaf(wv.x, v.x, fmaf(wv.y, v.y, fmaf(wv.z, v.z, fmaf(wv.w, v.w, acc2))));
        v = i3[c]; acc3 = fmaf(wv.x, v.x, fmaf(wv.y, v.y, fmaf(wv.z, v.z, fmaf(wv.w, v.w, acc3))));
    }
    x_lds[(rg * 4 + 0) * 65 + u] = acc0;
    x_lds[(rg * 4 + 1) * 65 + u] = acc1;
    x_lds[(rg * 4 + 2) * 65 + u] = acc2;
    x_lds[(rg * 4 + 3) * 65 + u] = acc3;
    x[(size_t)(row0 + rg * 4 + 0) * UNITS + u] = acc0;
    x[(size_t)(row0 + rg * 4 + 1) * UNITS + u] = acc1;
    x[(size_t)(row0 + rg * 4 + 2) * UNITS + u] = acc2;
    x[(size_t)(row0 + rg * 4 + 3) * UNITS + u] = acc3;
    __syncthreads();

    // e1/e2: 16 rows x 4 heads x 2 matrices = 128 tasks
    if (t < 128) {
        const int r = t >> 3;
        const int rem = t & 7;
        const int h = rem & 3;
        const bool first = rem < 4;
        const float* aw = aw_lds + (first ? 0 : UNITS * HEADS);
        float s = 0.f;
#pragma unroll 8
        for (int uu = 0; uu < UNITS; uu++)
            s += x_lds[r * 65 + uu] * aw[uu * HEADS + h];
        (first ? e1 : e2)[(size_t)(row0 + r) * HEADS + h] = s;
    }

    // partial column sums of x over this block's 16 rows
    if (t < 64) {
        float s = 0.f;
#pragma unroll
        for (int r = 0; r < 16; r++) s += x_lds[r * 65 + t];
        partial[b * 64 + t] = s;
    }
}

// ---------------------------------------------------------------------------
// Kernel 1b: S[u] = sum over 256 block-partials (256 threads, 4-way split)
// ---------------------------------------------------------------------------
__global__ __launch_bounds__(256) void k1b(const float* __restrict__ partial,
                                           float* __restrict__ S) {
    __shared__ float red[4][64];
    const int u = threadIdx.x & 63;
    const int q = threadIdx.x >> 6;
    float s = 0.f;
#pragma unroll 8
    for (int b = q; b < 256; b += 4) s += partial[b * 64 + u];
    red[q][u] = s;
    __syncthreads();
    if (threadIdx.x < 64) S[u] = red[0][u] + red[1][u] + red[2][u] + red[3][u];
}

// ---------------------------------------------------------------------------
// Kernel 2: per row i — scan adj row, compact neighbors, two-phase sparse
// softmax-corrected aggregation.
//   phase A: compute wgt[k][h] AND stage x rows of the chunk into LDS
//   phase B: pure-LDS tight loop: 2 LDS reads + 2 FMA per neighbor
// out[i, h*64+u] = relu((S[u]+acc)/(N+den)).
// ---------------------------------------------------------------------------
__global__ __launch_bounds__(256) void k2(const float* __restrict__ adj,
                                          const float* __restrict__ x,
                                          const float* __restrict__ e1,
                                          const float* __restrict__ e2,
                                          const float* __restrict__ S,
                                          float* __restrict__ out) {
    __shared__ unsigned short nbr[N_NODES];   // 8 KB — worst case all neighbors
    __shared__ float xs[CHUNK * UNITS];       // 16 KB — staged x rows for chunk
    __shared__ float wgt[CHUNK * 4];          // 1 KB — per-chunk weights (k-major)
    __shared__ int cnt;

    const int i = blockIdx.x;
    const int t = threadIdx.x;

    if (t == 0) cnt = 0;
    __syncthreads();

    // scan adjacency row: issue all 4 float4 loads up front (latency overlap)
    const float4* arow = (const float4*)(adj + (size_t)i * N_NODES);
    const float4 v0 = arow[t];
    const float4 v1 = arow[t + 256];
    const float4 v2 = arow[t + 512];
    const float4 v3 = arow[t + 768];
    {
        const int b0 = t * 4;
        if (v0.x != 0.f) nbr[atomicAdd(&cnt, 1)] = (unsigned short)(b0 + 0);
        if (v0.y != 0.f) nbr[atomicAdd(&cnt, 1)] = (unsigned short)(b0 + 1);
        if (v0.z != 0.f) nbr[atomicAdd(&cnt, 1)] = (unsigned short)(b0 + 2);
        if (v0.w != 0.f) nbr[atomicAdd(&cnt, 1)] = (unsigned short)(b0 + 3);
        const int b1 = (t + 256) * 4;
        if (v1.x != 0.f) nbr[atomicAdd(&cnt, 1)] = (unsigned short)(b1 + 0);
        if (v1.y != 0.f) nbr[atomicAdd(&cnt, 1)] = (unsigned short)(b1 + 1);
        if (v1.z != 0.f) nbr[atomicAdd(&cnt, 1)] = (unsigned short)(b1 + 2);
        if (v1.w != 0.f) nbr[atomicAdd(&cnt, 1)] = (unsigned short)(b1 + 3);
        const int b2 = (t + 512) * 4;
        if (v2.x != 0.f) nbr[atomicAdd(&cnt, 1)] = (unsigned short)(b2 + 0);
        if (v2.y != 0.f) nbr[atomicAdd(&cnt, 1)] = (unsigned short)(b2 + 1);
        if (v2.z != 0.f) nbr[atomicAdd(&cnt, 1)] = (unsigned short)(b2 + 2);
        if (v2.w != 0.f) nbr[atomicAdd(&cnt, 1)] = (unsigned short)(b2 + 3);
        const int b3 = (t + 768) * 4;
        if (v3.x != 0.f) nbr[atomicAdd(&cnt, 1)] = (unsigned short)(b3 + 0);
        if (v3.y != 0.f) nbr[atomicAdd(&cnt, 1)] = (unsigned short)(b3 + 1);
        if (v3.z != 0.f) nbr[atomicAdd(&cnt, 1)] = (unsigned short)(b3 + 2);
        if (v3.w != 0.f) nbr[atomicAdd(&cnt, 1)] = (unsigned short)(b3 + 3);
    }
    __syncthreads();

    const int n = cnt;
    const int h = t >> 6;
    const int u = t & 63;

    // e1 row for this node (broadcast float4)
    const float4 e1v = *(const float4*)(e1 + (size_t)i * HEADS);

    float acc = 0.f;   // sum_k wgt[k][h] * x[j_k][u]
    float den = 0.f;   // sum_k wgt[k][h]

    for (int base = 0; base < n; base += CHUNK) {
        const int m = min(n - base, CHUNK);

        // phase A1: weights for this chunk (threads 0..m-1)
        if (t < m) {
            const int j = nbr[base + t];
            const float4 e2v = *(const float4*)(e2 + (size_t)j * HEADS);
            float4 wv;
            wv.x = __expf(fmaxf(e1v.x + e2v.x, 0.f)) - 1.f;
            wv.y = __expf(fmaxf(e1v.y + e2v.y, 0.f)) - 1.f;
            wv.z = __expf(fmaxf(e1v.z + e2v.z, 0.f)) - 1.f;
            wv.w = __expf(fmaxf(e1v.w + e2v.w, 0.f)) - 1.f;
            *(float4*)(wgt + t * 4) = wv;
        }
        // phase A2: stage x rows of the chunk (coalesced: 64 lanes = one row)
        for (int idx = t; idx < m * UNITS; idx += 256) {
            const int k = idx >> 6;
            const int uu = idx & 63;
            xs[idx] = x[(size_t)nbr[base + k] * UNITS + uu];
        }
        __syncthreads();

        // phase B: pure-LDS tight loop
#pragma unroll 8
        for (int k = 0; k < m; k++) {
            const float wv = wgt[k * 4 + h];       // LDS broadcast (h wave-uniform)
            den += wv;
            acc = fmaf(wv, xs[k * UNITS + u], acc); // conflict-free (2-way, free)
        }
        __syncthreads();   // protect wgt/xs before next chunk overwrites
    }

    const float numer = S[u] + acc;
    const float denom = (float)N_NODES + den;
    out[(size_t)i * (HEADS * UNITS) + t] = fmaxf(numer / denom, 0.f);
}

// ---------------------------------------------------------------------------
extern "C" void kernel_launch(void* const* d_in, const int* in_sizes, int n_in,
                              void* d_out, int out_size, void* d_ws, size_t ws_size,
                              hipStream_t stream) {
    const float* inputs = (const float*)d_in[0];
    const float* adj    = (const float*)d_in[1];
    const float* w      = (const float*)d_in[2];
    const float* aw1    = (const float*)d_in[3];
    const float* aw2    = (const float*)d_in[4];
    float* out = (float*)d_out;

    // workspace layout (floats): x[262144] | e1[16384] | e2[16384] | partial[16384] | S[64]
    float* ws = (float*)d_ws;
    float* x       = ws;
    float* e1      = ws + 262144;
    float* e2      = ws + 262144 + 16384;
    float* partial = ws + 262144 + 2 * 16384;
    float* S       = ws + 262144 + 3 * 16384;

    k1<<<256, 256, 0, stream>>>(inputs, w, aw1, aw2, x, e1, e2, partial);
    k1b<<<1, 256, 0, stream>>>(partial, S);
    k2<<<N_NODES, 256, 0, stream>>>(adj, x, e1, e2, S, out);
}